// Round 8
// baseline (103.935 us; speedup 1.0000x reference)
//
#include <hip/hip_runtime.h>

#define NEXP  64
#define NTOK  32768
#define TOPK  2
#define NFLAT (NTOK * TOPK)   // 65536
#define DM    1024
#define NBLK  256
#define EPB   (NFLAT / NBLK)  // 256

typedef float v4f __attribute__((ext_vector_type(4)));

// Output layout (float32, concatenated):
#define O1 ((size_t)NFLAT * DM)
#define O2 (O1 + NFLAT)
#define O3 (O2 + NFLAT)

// ws layout (ints)
#define WS_CNT 0                      // 2 barrier counters (memset per call)
#define WS_DET 8                      // NBLK per-block detect OR slots
#define WS_BC  (WS_DET + NBLK)        // NBLK*NEXP block histograms

// All-blocks-resident global barrier (256 blocks x 8 waves on 256 CUs).
__device__ __forceinline__ void gbar(int* cnt) {
    __syncthreads();
    if (threadIdx.x == 0) {
        __threadfence();                       // release: hist/det visible
        atomicAdd(cnt, 1);
        while (atomicAdd(cnt, 0) < NBLK) __builtin_amdgcn_s_sleep(1);
        __threadfence();                       // acquire
    }
    __syncthreads();
}

// One persistent kernel: detect int32/int64 routing layout, per-block
// histogram, per-block expert base offsets, stable-rank scatter, row copy.
// Block b owns flat entries [256b, 256b+256) = tokens [128b, 128b+128).
__global__ void __launch_bounds__(512)
k_all(const int* __restrict__ routing, int* __restrict__ ws,
      const float* __restrict__ hidden, float* __restrict__ out) {
    __shared__ int se[EPB];              // raw word / later expert id
    __shared__ int dstSh[EPB];
    __shared__ int s1h[4][NEXP], s2h[4][NEXP];
    __shared__ int boSh[NEXP];
    __shared__ int h[NEXP];
    __shared__ int flagSh;
    const int t = threadIdx.x;
    const int b = blockIdx.x;

    // ---- P0: load this block's word range [256b, 256b+256) once.
    // Safe under both layouts (words [0, NFLAT) always exist). Under int64
    // these words' odd halves are entry hi-words (all zero); under int32
    // they are the entry values themselves.
    int w = 0;
    if (t < EPB) { w = routing[b * EPB + t]; se[t] = w; }
    // detect OR of odd words, wave-reduced
    unsigned long long ball = __ballot((t < EPB) && (t & 1) && (w != 0));
    if (t == 0) flagSh = 0;
    __syncthreads();
    if ((t & 63) == 0 && ball) atomicOr(&flagSh, 1);
    __syncthreads();
    if (t == 0) ws[WS_DET + b] = flagSh;

    // ---- B1: all detect slots visible.
    gbar(&ws[WS_CNT + 0]);

    // ---- P1: resolve stride (1 = int32, 2 = int64 words).
    if (t == 0) flagSh = 0;
    __syncthreads();
    if (t < NBLK && ws[WS_DET + t] != 0) atomicOr(&flagSh, 1);
    if (t < NEXP) h[t] = 0;
    __syncthreads();
    const int stride = flagSh ? 1 : 2;

    // ---- P2: entries + per-block histogram.
    if (t < EPB) {
        int e = (stride == 1) ? se[t] : routing[(size_t)(b * EPB + t) * 2];
        se[t] = e;
        atomicAdd(&h[e], 1);
    }
    __syncthreads();
    if (t < NEXP) ws[WS_BC + b * NEXP + t] = h[t];

    // ---- B2: all histograms visible.
    gbar(&ws[WS_CNT + 1]);

    // ---- P3: per-block expert base offsets from all 256 histograms.
    if (t < 256) {
        int e = t & 63, c = t >> 6;
        int s1 = 0, s2 = 0;
        #pragma unroll 8
        for (int r = c * 64; r < c * 64 + 64; ++r) {
            int v = ws[WS_BC + r * NEXP + e];
            s2 += v;
            s1 += (r < b) ? v : 0;
        }
        s1h[c][e] = s1; s2h[c][e] = s2;
    }
    __syncthreads();
    if (t < 64) {
        int e = t;
        int pre = s1h[0][e] + s1h[1][e] + s1h[2][e] + s1h[3][e];
        int tot = s2h[0][e] + s2h[1][e] + s2h[2][e] + s2h[3][e];
        int x = tot;
        #pragma unroll
        for (int d = 1; d < 64; d <<= 1) {
            int y = __shfl_up(x, d, 64);
            if (e >= d) x += y;
        }
        boSh[e] = (x - tot) + pre;          // expert prefix + prior blocks
        if (b == 0) out[O3 + e] = (float)tot;
    }
    __syncthreads();

    // ---- P4: stable rank within block + index outputs.
    if (t < EPB) {
        int e = se[t];
        int rank = 0;
        for (int j = 0; j < t; ++j) rank += (se[j] == e) ? 1 : 0;
        int dst = boSh[e] + rank;
        dstSh[t] = dst;
        int i = b * EPB + t;
        out[O1 + dst] = (float)i;
        out[O2 + i] = (float)i;
    }
    __syncthreads();

    // ---- P5: copy. Temporal loads (hidden LLC-resident across replays),
    // nontemporal stores (write-once stream, no RFO).
    const int half = t >> 8;     // which of 2 tokens this iteration
    const int lt = t & 255;      // float4 slot within the row
    #pragma unroll 4
    for (int k = 0; k < 128; k += 2) {
        int tokLocal = k + half;
        int tok = b * 128 + tokLocal;
        const v4f* src = (const v4f*)(hidden + (size_t)tok * DM);
        v4f v = src[lt];
        int d0 = dstSh[2 * tokLocal];
        int d1 = dstSh[2 * tokLocal + 1];
        __builtin_nontemporal_store(v, (v4f*)(out + (size_t)d0 * DM) + lt);
        __builtin_nontemporal_store(v, (v4f*)(out + (size_t)d1 * DM) + lt);
    }
}

extern "C" void kernel_launch(void* const* d_in, const int* in_sizes, int n_in,
                              void* d_out, int out_size, void* d_ws, size_t ws_size,
                              hipStream_t stream) {
    const float* hidden = (const float*)d_in[0];
    const int* routing = (const int*)d_in[1];
    float* out = (float*)d_out;
    int* ws = (int*)d_ws;

    hipMemsetAsync(ws + WS_CNT, 0, 2 * sizeof(int), stream);
    k_all<<<NBLK, 512, 0, stream>>>(routing, ws, hidden, out);
}

// Round 9
// 91.959 us; speedup vs baseline: 1.1302x; 1.1302x over previous
//
#include <hip/hip_runtime.h>

#define NEXP  64
#define NTOK  32768
#define TOPK  2
#define NFLAT (NTOK * TOPK)   // 65536
#define DM    1024
#define NBLK  256
#define EPB   (NFLAT / NBLK)  // 256
#define DETBLK 64

typedef float v4f __attribute__((ext_vector_type(4)));

// Output layout (float32, concatenated):
#define O1 ((size_t)NFLAT * DM)
#define O2 (O1 + NFLAT)
#define O3 (O2 + NFLAT)

// ws layout (ints)
#define WS_DET 0                      // DETBLK per-block detect OR slots
#define WS_BC  (WS_DET + DETBLK)      // NBLK*NEXP block histograms

// Detect int64 vs int32 routing layout. Reads only words [0, NFLAT) (safe
// under both layouts). int64 -> odd words (hi halves of elems 0..32767) all 0.
__global__ void k_detect(const int4* __restrict__ routing4, int* __restrict__ ws) {
    __shared__ int o;
    int t = threadIdx.x;
    if (t == 0) o = 0;
    __syncthreads();
    int k = blockIdx.x * 256 + t;   // 64 blocks * 256 = 16384 int4 = NFLAT words
    int4 w = routing4[k];
    int acc = w.y | w.w;
    if (__any(acc != 0)) { if ((t & 63) == 0) atomicOr(&o, 1); }
    __syncthreads();
    if (t == 0) ws[WS_DET + blockIdx.x] = o;
}

__device__ __forceinline__ int get_stride(const int* ws) {
    __shared__ int strideSh;
    int t = threadIdx.x;
    if (t < 64) {
        int v = ws[WS_DET + t];
        unsigned long long b = __ballot(v != 0);
        if (t == 0) strideSh = b ? 1 : 2;
    }
    __syncthreads();
    return strideSh;
}

__global__ void k_hist(const int* __restrict__ routing, int* __restrict__ ws) {
    __shared__ int h[NEXP];
    int t = threadIdx.x;
    const int stride = get_stride(ws);
    if (t < NEXP) h[t] = 0;
    __syncthreads();
    int i = blockIdx.x * EPB + t;
    int e = routing[(size_t)i * stride];
    atomicAdd(&h[e], 1);
    __syncthreads();
    if (t < NEXP) ws[WS_BC + blockIdx.x * NEXP + t] = h[t];
}

// Fused: per-block expert base offsets + stable-rank scatter + dst-ordered
// row copy. Block b owns entries [256b, 256b+256) = tokens [128b, 128b+128).
__global__ void __launch_bounds__(512)
k_main(const int* __restrict__ routing, const int* __restrict__ ws,
       const float* __restrict__ hidden, float* __restrict__ out) {
    __shared__ int se[EPB];
    __shared__ int dstSh[EPB];
    __shared__ int orderSh[EPB];          // entry index sorted by dst
    __shared__ int s1h[4][NEXP], s2h[4][NEXP];
    __shared__ int boSh[NEXP], loSh[NEXP];
    const int t = threadIdx.x;
    const int b = blockIdx.x;
    const int stride = get_stride(ws);

    if (t < EPB) {
        int i = b * EPB + t;
        se[t] = routing[(size_t)i * stride];
    }
    // Expert base offsets: wave c sums hist quarter [64c, 64c+64).
    if (t < 256) {
        int e = t & 63, c = t >> 6;
        int s1 = 0, s2 = 0;
        #pragma unroll 8
        for (int r = c * 64; r < c * 64 + 64; ++r) {
            int v = ws[WS_BC + r * NEXP + e];
            s2 += v;
            s1 += (r < b) ? v : 0;
        }
        s1h[c][e] = s1; s2h[c][e] = s2;
    }
    __syncthreads();
    if (t < 64) {
        int e = t;
        int pre = s1h[0][e] + s1h[1][e] + s1h[2][e] + s1h[3][e];
        int tot = s2h[0][e] + s2h[1][e] + s2h[2][e] + s2h[3][e];
        int hb = ws[WS_BC + b * NEXP + e];    // own histogram row
        // exclusive prefix over experts of tot (global) and hb (local)
        int x = tot, y = hb;
        #pragma unroll
        for (int d = 1; d < 64; d <<= 1) {
            int xx = __shfl_up(x, d, 64);
            int yy = __shfl_up(y, d, 64);
            if (e >= d) { x += xx; y += yy; }
        }
        boSh[e] = (x - tot) + pre;            // global expert base for this block
        loSh[e] = y - hb;                     // local (in-block) expert base
        if (b == 0) out[O3 + e] = (float)tot;
    }
    __syncthreads();
    // Stable rank within block + index outputs + dst-sorted order.
    if (t < EPB) {
        int e = se[t];
        int rank = 0;
        for (int j = 0; j < t; ++j) rank += (se[j] == e) ? 1 : 0;
        int dst = boSh[e] + rank;
        dstSh[t] = dst;
        orderSh[loSh[e] + rank] = t;          // counting-sort permutation
        int i = b * EPB + t;
        out[O1 + dst] = (float)i;
        out[O2 + i] = (float)i;
    }
    __syncthreads();
    // Copy in destination order: writes form sequential runs per expert.
    // Each entry = one output row; source row read from LLC (2x read trade).
    const int half = t >> 8;     // which of 2 entries this iteration
    const int lt = t & 255;      // float4 slot within the row
    #pragma unroll 2
    for (int p = 0; p < EPB; p += 2) {
        int pe = p + half;
        int ts = orderSh[pe];
        int srcTok = (b * EPB + ts) >> 1;
        const v4f* src = (const v4f*)(hidden + (size_t)srcTok * DM);
        v4f v = src[lt];
        int d = dstSh[ts];
        __builtin_nontemporal_store(v, (v4f*)(out + (size_t)d * DM) + lt);
    }
}

extern "C" void kernel_launch(void* const* d_in, const int* in_sizes, int n_in,
                              void* d_out, int out_size, void* d_ws, size_t ws_size,
                              hipStream_t stream) {
    const float* hidden = (const float*)d_in[0];
    const int* routing = (const int*)d_in[1];
    float* out = (float*)d_out;
    int* ws = (int*)d_ws;

    k_detect<<<DETBLK, 256, 0, stream>>>((const int4*)routing, ws);
    k_hist<<<NBLK, EPB, 0, stream>>>(routing, ws);
    k_main<<<NBLK, 512, 0, stream>>>(routing, ws, hidden, out);
}

// Round 10
// 80.553 us; speedup vs baseline: 1.2903x; 1.1416x over previous
//
#include <hip/hip_runtime.h>

#define NEXP  64
#define NTOK  32768
#define TOPK  2
#define NFLAT (NTOK * TOPK)   // 65536
#define DM    1024
#define NBLK  256
#define EPB   (NFLAT / NBLK)  // 256

typedef float v4f __attribute__((ext_vector_type(4)));

// Output layout (float32, concatenated):
#define O1 ((size_t)NFLAT * DM)
#define O2 (O1 + NFLAT)
#define O3 (O2 + NFLAT)

// Single self-sufficient kernel. Every block reads the whole routing array
// (256-512 KB, L2-resident; L2 BW is off the HBM fabric) and independently
// computes: int32/int64 layout detect, global expert bases, its own block's
// per-expert prefix, stable ranks, index outputs, and the row copy.
// Block b owns flat entries [256b, 256b+256) = tokens [128b, 128b+128).
__global__ void __launch_bounds__(512)
k_all(const int* __restrict__ routing, const float* __restrict__ hidden,
      float* __restrict__ out) {
    __shared__ int histLow[NEXP];   // entries with flat idx <  myBase, per expert
    __shared__ int histHigh[NEXP];  // entries with flat idx >= myBase, per expert
    __shared__ int se[EPB];
    __shared__ int dstSh[EPB];
    __shared__ int boSh[NEXP];
    __shared__ int flagSh;
    const int t = threadIdx.x;
    const int b = blockIdx.x;
    const int myBase = b * EPB;

    if (t == 0) flagSh = 0;
    if (t < NEXP) { histLow[t] = 0; histHigh[t] = 0; }
    __syncthreads();

    // ---- Pass 1: detect. OR of odd words over [0, NFLAT) (safe under both
    // layouts; int64 -> these are hi halves of entries 0..32767, all zero).
    {
        const int4* r4 = (const int4*)routing;
        int acc = 0;
        #pragma unroll 8
        for (int k = 0; k < 32; ++k) {        // 32*512 = 16384 int4 = NFLAT words
            int4 w = r4[k * 512 + t];
            acc |= w.y | w.w;
        }
        if (__any(acc != 0)) { if ((t & 63) == 0) atomicOr(&flagSh, 1); }
    }
    __syncthreads();
    const int stride = flagSh ? 1 : 2;        // 1=int32, 2=int64 words

    // my block's entries (lo words under int64)
    if (t < EPB) se[t] = routing[(size_t)(myBase + t) * stride];

    // ---- Pass 2: full-array histogram, split at myBase (one atomic/entry).
    if (stride == 1) {
        const int4* r4 = (const int4*)routing;
        #pragma unroll 4
        for (int k = 0; k < 32; ++k) {
            int idx4 = k * 512 + t;
            int4 w = r4[idx4];
            int i0 = idx4 * 4;                // first entry index of this int4
            atomicAdd((i0 + 0 < myBase) ? &histLow[w.x] : &histHigh[w.x], 1);
            atomicAdd((i0 + 1 < myBase) ? &histLow[w.y] : &histHigh[w.y], 1);
            atomicAdd((i0 + 2 < myBase) ? &histLow[w.z] : &histHigh[w.z], 1);
            atomicAdd((i0 + 3 < myBase) ? &histLow[w.w] : &histHigh[w.w], 1);
        }
    } else {
        const int4* r4 = (const int4*)routing;
        #pragma unroll 4
        for (int k = 0; k < 64; ++k) {        // 64*512 = 32768 int4 = 2*NFLAT words
            int idx4 = k * 512 + t;
            int4 w = r4[idx4];
            int i0 = idx4 * 2;                // entries = even words
            atomicAdd((i0 + 0 < myBase) ? &histLow[w.x] : &histHigh[w.x], 1);
            atomicAdd((i0 + 1 < myBase) ? &histLow[w.z] : &histHigh[w.z], 1);
        }
    }
    __syncthreads();

    // ---- Expert base offsets: wave-wide exclusive scan of totals + my prefix.
    if (t < 64) {
        int e = t;
        int low = histLow[e], high = histHigh[e];
        int tot = low + high;
        int x = tot;
        #pragma unroll
        for (int d = 1; d < 64; d <<= 1) {
            int y = __shfl_up(x, d, 64);
            if (e >= d) x += y;
        }
        boSh[e] = (x - tot) + low;            // global expert base + prior entries
        if (b == 0) out[O3 + e] = (float)tot;
    }
    __syncthreads();

    // ---- Stable rank within block + index outputs.
    if (t < EPB) {
        int e = se[t];
        int rank = 0;
        for (int j = 0; j < t; ++j) rank += (se[j] == e) ? 1 : 0;
        int dst = boSh[e] + rank;
        dstSh[t] = dst;
        int i = myBase + t;
        out[O1 + dst] = (float)i;
        out[O2 + i] = (float)i;
    }
    __syncthreads();

    // ---- Copy: temporal loads (hidden LLC-resident across replays),
    // nontemporal stores (write-once stream; no RFO, no LLC pollution).
    const int half = t >> 8;     // which of 2 tokens this iteration
    const int lt = t & 255;      // float4 slot within the row
    #pragma unroll 4
    for (int k = 0; k < 128; k += 2) {
        int tokLocal = k + half;
        int tok = b * 128 + tokLocal;
        const v4f* src = (const v4f*)(hidden + (size_t)tok * DM);
        v4f v = src[lt];
        int d0 = dstSh[2 * tokLocal];
        int d1 = dstSh[2 * tokLocal + 1];
        __builtin_nontemporal_store(v, (v4f*)(out + (size_t)d0 * DM) + lt);
        __builtin_nontemporal_store(v, (v4f*)(out + (size_t)d1 * DM) + lt);
    }
}

extern "C" void kernel_launch(void* const* d_in, const int* in_sizes, int n_in,
                              void* d_out, int out_size, void* d_ws, size_t ws_size,
                              hipStream_t stream) {
    const float* hidden = (const float*)d_in[0];
    const int* routing = (const int*)d_in[1];
    float* out = (float*)d_out;

    k_all<<<NBLK, 512, 0, stream>>>(routing, hidden, out);
}

// Round 11
// 74.846 us; speedup vs baseline: 1.3886x; 1.0762x over previous
//
#include <hip/hip_runtime.h>

#define NEXP  64
#define NTOK  32768
#define TOPK  2
#define NFLAT (NTOK * TOPK)   // 65536
#define DM    1024
#define NBLK  256
#define EPB   (NFLAT / NBLK)  // 256

typedef float v4f __attribute__((ext_vector_type(4)));

// Output layout (float32, concatenated):
#define O1 ((size_t)NFLAT * DM)
#define O2 (O1 + NFLAT)
#define O3 (O2 + NFLAT)

// ws layout (ints)
#define WS_DET 0                        // NBLK per-block detect OR slots
#define WS_H32 (WS_DET + NBLK)          // NBLK*NEXP histograms (int32 hyp.)
#define WS_H64 (WS_H32 + NBLK * NEXP)   // NBLK*NEXP histograms (int64 hyp.)

// Combined detect + dual-hypothesis histogram. Block b:
//  - odd-word OR over words [256b, 256b+256)  -> det slot (int64 => all 0)
//  - hist32 from words [256b, 256b+256)        (entries if layout is int32)
//  - hist64 from even words of [512b, 512b+512) (entries if layout is int64)
// All reads in-range under both layouts; entry values < 64 under both
// interpretations (&63 for hardening).
__global__ void k_hist(const int* __restrict__ routing, int* __restrict__ ws) {
    __shared__ int h32[NEXP], h64[NEXP];
    __shared__ int oSh;
    const int t = threadIdx.x;
    const int b = blockIdx.x;
    if (t == 0) oSh = 0;
    if (t < NEXP) { h32[t] = 0; h64[t] = 0; }
    __syncthreads();
    int w32 = routing[b * EPB + t];
    int w64 = routing[(size_t)(b * EPB + t) * 2];
    int odd = (t & 1) ? w32 : 0;
    if (__any(odd != 0)) { if ((t & 63) == 0) atomicOr(&oSh, 1); }
    atomicAdd(&h32[w32 & 63], 1);
    atomicAdd(&h64[w64 & 63], 1);
    __syncthreads();
    if (t == 0) ws[WS_DET + b] = oSh;
    if (t < NEXP) {
        ws[WS_H32 + b * NEXP + t] = h32[t];
        ws[WS_H64 + b * NEXP + t] = h64[t];
    }
}

// Fused: stride resolve + per-block expert base offsets + stable-rank
// scatter + row copy. Block b owns entries [256b,256b+256) = tokens
// [128b, 128b+128).
__global__ void __launch_bounds__(512)
k_main(const int* __restrict__ routing, const int* __restrict__ ws,
       const float* __restrict__ hidden, float* __restrict__ out) {
    __shared__ int se[EPB];
    __shared__ int dstSh[EPB];
    __shared__ int s1h[4][NEXP], s2h[4][NEXP];
    __shared__ int boSh[NEXP];
    __shared__ int flagSh;
    const int t = threadIdx.x;
    const int b = blockIdx.x;

    // Resolve stride from the 256 det slots (any nonzero -> int32).
    if (t == 0) flagSh = 0;
    __syncthreads();
    if (t < NBLK && ws[WS_DET + t] != 0) atomicOr(&flagSh, 1);
    __syncthreads();
    const int stride = flagSh ? 1 : 2;           // 1=int32, 2=int64 words
    const int hbase = flagSh ? WS_H32 : WS_H64;  // matching histogram table

    if (t < EPB) {
        int i = b * EPB + t;
        se[t] = routing[(size_t)i * stride];
    }
    // Expert base offsets: wave c sums hist quarter [64c, 64c+64).
    if (t < 256) {
        int e = t & 63, c = t >> 6;
        int s1 = 0, s2 = 0;
        #pragma unroll 8
        for (int r = c * 64; r < c * 64 + 64; ++r) {
            int v = ws[hbase + r * NEXP + e];
            s2 += v;
            s1 += (r < b) ? v : 0;
        }
        s1h[c][e] = s1; s2h[c][e] = s2;
    }
    __syncthreads();
    if (t < 64) {
        int e = t;
        int pre = s1h[0][e] + s1h[1][e] + s1h[2][e] + s1h[3][e];
        int tot = s2h[0][e] + s2h[1][e] + s2h[2][e] + s2h[3][e];
        int x = tot;
        #pragma unroll
        for (int d = 1; d < 64; d <<= 1) {
            int y = __shfl_up(x, d, 64);
            if (e >= d) x += y;
        }
        boSh[e] = (x - tot) + pre;          // expert prefix + prior blocks
        if (b == 0) out[O3 + e] = (float)tot;
    }
    __syncthreads();
    // Stable rank within block + index outputs.
    if (t < EPB) {
        int e = se[t];
        int rank = 0;
        for (int j = 0; j < t; ++j) rank += (se[j] == e) ? 1 : 0;
        int dst = boSh[e] + rank;
        dstSh[t] = dst;
        int i = b * EPB + t;
        out[O1 + dst] = (float)i;
        out[O2 + i] = (float)i;
    }
    __syncthreads();
    // Copy: temporal loads (hidden LLC-resident across replays),
    // nontemporal stores (write-once stream; no RFO, no LLC pollution).
    const int half = t >> 8;     // which of 2 tokens this iteration
    const int lt = t & 255;      // float4 slot within the row
    #pragma unroll 4
    for (int k = 0; k < 128; k += 2) {
        int tokLocal = k + half;
        int tok = b * 128 + tokLocal;
        const v4f* src = (const v4f*)(hidden + (size_t)tok * DM);
        v4f v = src[lt];
        int d0 = dstSh[2 * tokLocal];
        int d1 = dstSh[2 * tokLocal + 1];
        __builtin_nontemporal_store(v, (v4f*)(out + (size_t)d0 * DM) + lt);
        __builtin_nontemporal_store(v, (v4f*)(out + (size_t)d1 * DM) + lt);
    }
}

extern "C" void kernel_launch(void* const* d_in, const int* in_sizes, int n_in,
                              void* d_out, int out_size, void* d_ws, size_t ws_size,
                              hipStream_t stream) {
    const float* hidden = (const float*)d_in[0];
    const int* routing = (const int*)d_in[1];
    float* out = (float*)d_out;
    int* ws = (int*)d_ws;

    k_hist<<<NBLK, EPB, 0, stream>>>(routing, ws);
    k_main<<<NBLK, 512, 0, stream>>>(routing, ws, hidden, out);
}